// Round 5
// baseline (158.495 us; speedup 1.0000x reference)
//
#include <hip/hip_runtime.h>
#include <hip/hip_bf16.h>
#include <math.h>

// spatialAttention: B=512, P=128, D=64, domain 12x12, W [64,128], out [512,128,64] f32
#define NB 512
#define NP 128
#define ND 64
#define EPSF 1e-5f
// bf16-element row stride for MFMA-read LDS arrays: 136 elems = 272 B.
// 272 % 16 == 0 -> every short8 frag access is 16B-aligned; frag-read bank
// aliasing is 2-way (free per m136).
#define SW 136

typedef __attribute__((ext_vector_type(8))) short short8;   // 8 bf16 = 4 VGPRs
typedef __attribute__((ext_vector_type(4))) float f32x4;    // MFMA accumulator

__device__ __forceinline__ short f2bf(float x) {
    __hip_bfloat16 h = __float2bfloat16(x);
    return *reinterpret_cast<short*>(&h);
}

// bin = floor(x/30) clamped to [0,11], matching numpy's f32 semantics
// floor(RN32(x/30)). f64 multiply by RN64(1/30) then RN to f32 agrees with
// RN32(x/30) except with ~2^-29/elem probability (vs ~1e-6 for f32 rcp-mul,
// which WOULD flip ~20 bins across 16.8M elems). x >= 0 here so (int) = floor.
__device__ __forceinline__ int bin30(float x) {
    float t = (float)((double)x * (1.0 / 30.0));
    int i = (int)t;
    return i < 0 ? 0 : (i > 11 ? 11 : i);
}

__device__ __forceinline__ float fast_tanh(float x) {
    // tanh(x) = 1 - 2/(exp(2x)+1); native exp + native rcp (~1 ulp each).
    float e = __expf(2.0f * x);
    return 1.0f - 2.0f * __builtin_amdgcn_rcpf(e + 1.0f);
}

// W as bf16 [64][128], produced by prep kernel each launch (graph-safe:
// plain device-global memory, rewritten before every main-kernel read).
__device__ __align__(16) short g_wbf[ND * 2 * ND];

__global__ __launch_bounds__(256) void prep_w(const float* __restrict__ W) {
    int idx = blockIdx.x * 256 + threadIdx.x;     // 2048 float4
    float4 v = ((const float4*)W)[idx];
    short4 s4;
    s4.x = f2bf(v.x); s4.y = f2bf(v.y); s4.z = f2bf(v.z); s4.w = f2bf(v.w);
    *(short4*)&g_wbf[idx * 4] = s4;
}

// 2 blocks per batch (rows [half*64, half*64+64)), 256 threads = 4 waves,
// wave owns 16 rows. LDS ~36 KB -> 4 blocks/CU (grid 1024 = exactly 4/CU),
// 16 waves/CU. Single __syncthreads.
//   phase 1: UNNORMALIZED E = exp(w)+eps (masked) -> bf16 LDS, no cross-lane
//            ops (softmax denominators come from MFMA ones-row-sums, since
//            (E/s)@h = diag(1/s)(E@h)).
//   phase 2: E@h + row sums via MFMA (K=128); scale by 1/(s+eps) during the
//            C->A layout round-trip; append h -> fused [wh|h].
//   phase 3: out = fast_tanh(fused @ W^T + b), W-frags straight from g_wbf
//            (16 KB, L2-resident, shared by all 1024 blocks).
__global__ __launch_bounds__(256, 4) void spatial_attn_kernel(
    const float* __restrict__ hidden,   // [B,P,D]
    const float* __restrict__ dist,     // [B,P,P]
    const float* __restrict__ bear,     // [B,P,P]
    const float* __restrict__ head,     // [B,P,P]
    const float* __restrict__ smask,    // [B,P]
    const float* __restrict__ domain,   // [12,12]
    const float* __restrict__ bias,     // [D]
    float* __restrict__ out)            // [B,P,D]
{
    __shared__ __align__(16) short s_w[64 * SW];   // 17408 B: E, then [wh|h]
    __shared__ __align__(16) short s_hT[ND * SW];  // 17408 B: s_hT[d][q] = h[q][d]
    __shared__ float s_dom[144];
    __shared__ float s_mask[NP];

    const int blk  = blockIdx.x;
    const int b    = blk >> 1;
    const int half = blk & 1;
    const int tid  = threadIdx.x;
    const int lane = tid & 63;
    const int wave = tid >> 6;          // 0..3
    const int quad = lane >> 4;
    const int l16  = lane & 15;

    // ---- stage hidden^T as bf16, swizzled so transpose writes are 4-way
    //      (not 16-way) bank-conflicted; loads still cover contiguous 4KB/iter ----
    {
        const float4* hsrc = (const float4*)(hidden + (size_t)b * NP * ND);
        #pragma unroll
        for (int i = 0; i < 8; ++i) {
            int idx = i * 256 + ((tid & 15) * 16 + (tid >> 4));
            float4 v = hsrc[idx];
            int q = idx >> 4;                 // = i*16 + (tid&15)
            int d = (idx & 15) * 4;           // = (tid>>4)*4
            s_hT[(d + 0) * SW + q] = f2bf(v.x);
            s_hT[(d + 1) * SW + q] = f2bf(v.y);
            s_hT[(d + 2) * SW + q] = f2bf(v.z);
            s_hT[(d + 3) * SW + q] = f2bf(v.w);
        }
    }
    if (tid < 144) s_dom[tid] = domain[tid];
    if (tid < NP)  s_mask[tid] = smask[b * NP + tid];
    __syncthreads();   // the only block-wide barrier

    const int R0L = wave * 16;            // local row base (of 64)
    const int P0  = half * 64 + R0L;      // row base within batch (of 128)
    const size_t rowbase = (size_t)b * NP * NP;
    const float mq0 = s_mask[lane], mq1 = s_mask[lane + 64];

    // ---- phase 1: unnormalized masked exp, 16 own rows, no cross-lane ops ----
    for (int j0 = 0; j0 < 16; j0 += 4) {
        #pragma unroll
        for (int r = 0; r < 4; ++r) {
            const int p = P0 + j0 + r;              // row within batch
            const int rl = R0L + j0 + r;            // local row in s_w
            const size_t ro = rowbase + (size_t)p * NP;
            float dq0 = dist[ro + lane], dq1 = dist[ro + lane + 64];
            float bq0 = bear[ro + lane], bq1 = bear[ro + lane + 64];
            float hq0 = head[ro + lane], hq1 = head[ro + lane + 64];
            const float mp = s_mask[p];

            int i1 = bin30(hq0), i2 = bin30(bq0);
            float wv0 = s_dom[i1 * 12 + i2] - dq0;
            bool on0 = (wv0 > 0.0f) && (mp != 0.0f) && (mq0 != 0.0f) && (lane != p);
            float e0 = on0 ? (__expf(wv0) + EPSF) : EPSF;

            int k1 = bin30(hq1), k2 = bin30(bq1);
            float wv1 = s_dom[k1 * 12 + k2] - dq1;
            bool on1 = (wv1 > 0.0f) && (mp != 0.0f) && (mq1 != 0.0f) && ((lane + 64) != p);
            float e1 = on1 ? (__expf(wv1) + EPSF) : EPSF;

            s_w[rl * SW + lane]      = f2bf(e0);
            s_w[rl * SW + lane + 64] = f2bf(e1);
        }
    }

    // ---- phase 2: wh_unnorm = E @ h + ones-MFMA row sums (K=128) ----
    f32x4 acc[4], accs;
    #pragma unroll
    for (int tj = 0; tj < 4; ++tj) acc[tj] = (f32x4){0.f, 0.f, 0.f, 0.f};
    accs = (f32x4){0.f, 0.f, 0.f, 0.f};

    short8 ones;
    #pragma unroll
    for (int i = 0; i < 8; ++i) ones[i] = (short)0x3F80;  // bf16 1.0

    #pragma unroll
    for (int kb = 0; kb < 4; ++kb) {
        const int ko = kb * 32 + quad * 8;
        short8 a = *(const short8*)&s_w[(R0L + l16) * SW + ko];
        accs = __builtin_amdgcn_mfma_f32_16x16x32_bf16(a, ones, accs, 0, 0, 0);
        #pragma unroll
        for (int tj = 0; tj < 4; ++tj) {
            short8 bf = *(const short8*)&s_hT[(tj * 16 + l16) * SW + ko];
            acc[tj] = __builtin_amdgcn_mfma_f32_16x16x32_bf16(a, bf, acc[tj], 0, 0, 0);
        }
    }

    // C/D row = quad*4 + r; accs rows match lane-for-lane.
    float inv[4];
    #pragma unroll
    for (int r = 0; r < 4; ++r) inv[r] = 1.0f / (accs[r] + EPSF);

    // ---- build fused rows [wh | h] in s_w (wave-local; DS is in-order) ----
    #pragma unroll
    for (int tj = 0; tj < 4; ++tj)
        #pragma unroll
        for (int r = 0; r < 4; ++r) {
            int row = R0L + quad * 4 + r;
            s_w[row * SW + tj * 16 + l16] = f2bf(acc[tj][r] * inv[r]);
        }
    {
        const float* hb = hidden + ((size_t)b * NP + P0 - R0L) * ND;  // batch base + half offset
        #pragma unroll 4
        for (int i = 0; i < 16; ++i) {      // L2-warm coalesced re-read of own rows
            float hv = hb[(size_t)(R0L + i) * ND + lane];
            s_w[(R0L + i) * SW + 64 + lane] = f2bf(hv);
        }
    }

    // ---- phase 3: out = tanh(fused @ W^T + b), B-frags from g_wbf (L2) ----
    f32x4 acc2[4];
    #pragma unroll
    for (int tj = 0; tj < 4; ++tj) acc2[tj] = (f32x4){0.f, 0.f, 0.f, 0.f};

    #pragma unroll
    for (int kb = 0; kb < 4; ++kb) {
        const int ko = kb * 32 + quad * 8;
        short8 a = *(const short8*)&s_w[(R0L + l16) * SW + ko];
        #pragma unroll
        for (int tj = 0; tj < 4; ++tj) {
            short8 bf = *(const short8*)&g_wbf[(tj * 16 + l16) * (2 * ND) + ko];
            acc2[tj] = __builtin_amdgcn_mfma_f32_16x16x32_bf16(a, bf, acc2[tj], 0, 0, 0);
        }
    }

    float bvals[4];
    #pragma unroll
    for (int tj = 0; tj < 4; ++tj) bvals[tj] = bias[tj * 16 + l16];

    float* ob = out + ((size_t)b * NP + half * 64) * ND;
    #pragma unroll
    for (int tj = 0; tj < 4; ++tj)
        #pragma unroll
        for (int r = 0; r < 4; ++r) {
            int row = R0L + quad * 4 + r;
            ob[(size_t)row * ND + tj * 16 + l16] = fast_tanh(acc2[tj][r] + bvals[tj]);
        }
}

extern "C" void kernel_launch(void* const* d_in, const int* in_sizes, int n_in,
                              void* d_out, int out_size, void* d_ws, size_t ws_size,
                              hipStream_t stream) {
    const float* hidden = (const float*)d_in[0];
    const float* dist   = (const float*)d_in[1];
    const float* bear   = (const float*)d_in[2];
    const float* head   = (const float*)d_in[3];
    const float* smask  = (const float*)d_in[4];
    const float* domain = (const float*)d_in[5];
    const float* W      = (const float*)d_in[6];
    const float* bias   = (const float*)d_in[7];
    float* out = (float*)d_out;

    prep_w<<<dim3(8), dim3(256), 0, stream>>>(W);
    spatial_attn_kernel<<<dim3(NB * 2), dim3(256), 0, stream>>>(
        hidden, dist, bear, head, smask, domain, bias, out);
}

// Round 6
// 155.800 us; speedup vs baseline: 1.0173x; 1.0173x over previous
//
#include <hip/hip_runtime.h>
#include <hip/hip_bf16.h>
#include <math.h>

// spatialAttention: B=512, P=128, D=64, domain 12x12, W [64,128], out [512,128,64] f32
#define NB 512
#define NP 128
#define ND 64
#define EPSF 1e-5f
// bf16-element row stride for MFMA-read LDS arrays: 136 elems = 272 B.
// 272 % 16 == 0 -> every short8 frag access is 16B-aligned; frag-read bank
// aliasing is 2-way (free per m136).
#define SW 136

typedef __attribute__((ext_vector_type(8))) short short8;   // 8 bf16 = 4 VGPRs
typedef __attribute__((ext_vector_type(4))) float f32x4;    // MFMA accumulator

__device__ __forceinline__ short f2bf(float x) {
    __hip_bfloat16 h = __float2bfloat16(x);
    return *reinterpret_cast<short*>(&h);
}

// bin = floor(x/30) clamped to [0,11]. f64 multiply by RN64(1/30) then RN to
// f32 agrees with numpy's RN32(x/30) except w.p. ~2^-29/elem (f32 rcp-mul
// would flip ~20 bins across 16.8M elems). x >= 0 here so (int) = floor.
__device__ __forceinline__ int bin30(float x) {
    float t = (float)((double)x * (1.0 / 30.0));
    int i = (int)t;
    return i < 0 ? 0 : (i > 11 ? 11 : i);
}

__device__ __forceinline__ float fast_tanh(float x) {
    float e = __expf(2.0f * x);                    // ~1 ulp native exp
    return 1.0f - 2.0f * __builtin_amdgcn_rcpf(e + 1.0f);
}

// W as bf16 [64][128], produced by prep kernel each launch (graph-safe).
__device__ __align__(16) short g_wbf[ND * 2 * ND];

__global__ __launch_bounds__(256) void prep_w(const float* __restrict__ W) {
    int idx = blockIdx.x * 256 + threadIdx.x;     // 2048 float4
    float4 v = ((const float4*)W)[idx];
    short4 s4;
    s4.x = f2bf(v.x); s4.y = f2bf(v.y); s4.z = f2bf(v.z); s4.w = f2bf(v.w);
    *(short4*)&g_wbf[idx * 4] = s4;
}

// 2 blocks per batch (rows [half*64, half*64+64)), 256 threads = 4 waves,
// wave owns 16 rows. LDS ~36 KB -> 4 blocks/CU, 16 waves/CU, one barrier.
//   phase 1: UNNORMALIZED E = exp(w)+eps (masked) -> bf16 LDS. float4 loads:
//            2 contiguous rows per wave-iteration = 1KB/instr coalescing
//            (request-count, not bytes, limits per-CU BW — R5 post-mortem).
//   phase 2: E@h + ones-MFMA row sums (K=128); scale by 1/(s+eps) during the
//            C->A LDS round-trip; append h from s_hT columns (no global).
//   phase 3: out = fast_tanh(fused @ W^T + b), W-frags from g_wbf (L2-hot).
__global__ __launch_bounds__(256, 4) void spatial_attn_kernel(
    const float* __restrict__ hidden,   // [B,P,D]
    const float* __restrict__ dist,     // [B,P,P]
    const float* __restrict__ bear,     // [B,P,P]
    const float* __restrict__ head,     // [B,P,P]
    const float* __restrict__ smask,    // [B,P]
    const float* __restrict__ domain,   // [12,12]
    const float* __restrict__ bias,     // [D]
    float* __restrict__ out)            // [B,P,D]
{
    __shared__ __align__(16) short s_w[64 * SW];   // 17408 B: E, then [wh|h]
    __shared__ __align__(16) short s_hT[ND * SW];  // 17408 B: s_hT[d][q] = h[q][d]
    __shared__ float s_dom[144];
    __shared__ float s_mask[NP];

    const int blk  = blockIdx.x;
    const int b    = blk >> 1;
    const int half = blk & 1;
    const int tid  = threadIdx.x;
    const int lane = tid & 63;
    const int wave = tid >> 6;          // 0..3
    const int quad = lane >> 4;
    const int l16  = lane & 15;

    // ---- stage hidden^T as bf16 (swizzled: transpose writes 4-way not 16-way) ----
    {
        const float4* hsrc = (const float4*)(hidden + (size_t)b * NP * ND);
        #pragma unroll
        for (int i = 0; i < 8; ++i) {
            int idx = i * 256 + ((tid & 15) * 16 + (tid >> 4));
            float4 v = hsrc[idx];
            int q = idx >> 4;
            int d = (idx & 15) * 4;
            s_hT[(d + 0) * SW + q] = f2bf(v.x);
            s_hT[(d + 1) * SW + q] = f2bf(v.y);
            s_hT[(d + 2) * SW + q] = f2bf(v.z);
            s_hT[(d + 3) * SW + q] = f2bf(v.w);
        }
    }
    if (tid < 144) s_dom[tid] = domain[tid];
    if (tid < NP)  s_mask[tid] = smask[b * NP + tid];
    __syncthreads();   // the only block-wide barrier

    const int R0L = wave * 16;            // local row base (of 64)
    const int P0  = half * 64 + R0L;      // row base within batch (of 128)
    const size_t rowbase = (size_t)b * NP * NP;

    // Each lane owns 4 consecutive q of one of 2 rows per iteration.
    const int rsel = lane >> 5;           // 0 or 1: which of the 2 rows
    const int q0   = (lane & 31) * 4;     // column base within the row
    const float4 mqv = *(const float4*)&s_mask[q0];   // masks for q0..q0+3

    // ---- phase 1: unnormalized masked exp; 1KB/instr float4 streaming ----
    #pragma unroll 2
    for (int j0 = 0; j0 < 16; j0 += 2) {
        const int p  = P0 + j0 + rsel;                // row within batch
        const int rl = R0L + j0 + rsel;               // local row in s_w
        const size_t ro = rowbase + (size_t)p * NP + q0;
        float4 dq = *(const float4*)&dist[ro];
        float4 bq = *(const float4*)&bear[ro];
        float4 hq = *(const float4*)&head[ro];
        const float mp = s_mask[p];

        float hv[4] = {hq.x, hq.y, hq.z, hq.w};
        float bv[4] = {bq.x, bq.y, bq.z, bq.w};
        float dv[4] = {dq.x, dq.y, dq.z, dq.w};
        float mv[4] = {mqv.x, mqv.y, mqv.z, mqv.w};
        short ex[4];
        #pragma unroll
        for (int c = 0; c < 4; ++c) {
            int i1 = bin30(hv[c]), i2 = bin30(bv[c]);
            float wv = s_dom[i1 * 12 + i2] - dv[c];
            bool on = (wv > 0.0f) && (mp != 0.0f) && (mv[c] != 0.0f) && (q0 + c != p);
            ex[c] = f2bf(on ? (__expf(wv) + EPSF) : EPSF);
        }
        short4 res; res.x = ex[0]; res.y = ex[1]; res.z = ex[2]; res.w = ex[3];
        *(short4*)&s_w[rl * SW + q0] = res;           // 8B-aligned ds_write_b64
    }

    // ---- phase 2: wh_unnorm = E @ h + ones-MFMA row sums (K=128) ----
    f32x4 acc[4], accs;
    #pragma unroll
    for (int tj = 0; tj < 4; ++tj) acc[tj] = (f32x4){0.f, 0.f, 0.f, 0.f};
    accs = (f32x4){0.f, 0.f, 0.f, 0.f};

    short8 ones;
    #pragma unroll
    for (int i = 0; i < 8; ++i) ones[i] = (short)0x3F80;  // bf16 1.0

    #pragma unroll
    for (int kb = 0; kb < 4; ++kb) {
        const int ko = kb * 32 + quad * 8;
        short8 a = *(const short8*)&s_w[(R0L + l16) * SW + ko];
        accs = __builtin_amdgcn_mfma_f32_16x16x32_bf16(a, ones, accs, 0, 0, 0);
        #pragma unroll
        for (int tj = 0; tj < 4; ++tj) {
            short8 bf = *(const short8*)&s_hT[(tj * 16 + l16) * SW + ko];
            acc[tj] = __builtin_amdgcn_mfma_f32_16x16x32_bf16(a, bf, acc[tj], 0, 0, 0);
        }
    }

    // C/D row = quad*4 + r; accs rows match lane-for-lane.
    float inv[4];
    #pragma unroll
    for (int r = 0; r < 4; ++r) inv[r] = 1.0f / (accs[r] + EPSF);

    // ---- build fused rows [wh | h] in s_w (wave-local; DS is in-order) ----
    #pragma unroll
    for (int tj = 0; tj < 4; ++tj)
        #pragma unroll
        for (int r = 0; r < 4; ++r) {
            int row = R0L + quad * 4 + r;
            s_w[row * SW + tj * 16 + l16] = f2bf(acc[tj][r] * inv[r]);
        }
    // h columns straight from s_hT (bf16 passthrough; no global traffic).
    #pragma unroll 4
    for (int i = 0; i < 16; ++i)
        s_w[(R0L + i) * SW + 64 + lane] = s_hT[lane * SW + (P0 + i)];

    // ---- phase 3: out = tanh(fused @ W^T + b), B-frags from g_wbf (L2) ----
    f32x4 acc2[4];
    #pragma unroll
    for (int tj = 0; tj < 4; ++tj) acc2[tj] = (f32x4){0.f, 0.f, 0.f, 0.f};

    #pragma unroll
    for (int kb = 0; kb < 4; ++kb) {
        const int ko = kb * 32 + quad * 8;
        short8 a = *(const short8*)&s_w[(R0L + l16) * SW + ko];
        #pragma unroll
        for (int tj = 0; tj < 4; ++tj) {
            short8 bf = *(const short8*)&g_wbf[(tj * 16 + l16) * (2 * ND) + ko];
            acc2[tj] = __builtin_amdgcn_mfma_f32_16x16x32_bf16(a, bf, acc2[tj], 0, 0, 0);
        }
    }

    float bvals[4];
    #pragma unroll
    for (int tj = 0; tj < 4; ++tj) bvals[tj] = bias[tj * 16 + l16];

    float* ob = out + ((size_t)b * NP + half * 64) * ND;
    #pragma unroll
    for (int tj = 0; tj < 4; ++tj)
        #pragma unroll
        for (int r = 0; r < 4; ++r) {
            int row = R0L + quad * 4 + r;
            ob[(size_t)row * ND + tj * 16 + l16] = fast_tanh(acc2[tj][r] + bvals[tj]);
        }
}

extern "C" void kernel_launch(void* const* d_in, const int* in_sizes, int n_in,
                              void* d_out, int out_size, void* d_ws, size_t ws_size,
                              hipStream_t stream) {
    const float* hidden = (const float*)d_in[0];
    const float* dist   = (const float*)d_in[1];
    const float* bear   = (const float*)d_in[2];
    const float* head   = (const float*)d_in[3];
    const float* smask  = (const float*)d_in[4];
    const float* domain = (const float*)d_in[5];
    const float* W      = (const float*)d_in[6];
    const float* bias   = (const float*)d_in[7];
    float* out = (float*)d_out;

    prep_w<<<dim3(8), dim3(256), 0, stream>>>(W);
    spatial_attn_kernel<<<dim3(NB * 2), dim3(256), 0, stream>>>(
        hidden, dist, bear, head, smask, domain, bias, out);
}